// Round 13
// baseline (312.437 us; speedup 1.0000x reference)
//
#include <hip/hip_runtime.h>

// ---------------------------------------------------------------------------
// Fused NeRF MLP forward: 262144 rows, 63-in, 8x256 hidden + skip at L4->L5,
// 4-dim output. fp16 MFMA (16x16x32, swapped operands) with fp32 accum.
//
// R13: intra-block dual-tile anti-phase. 512-thr block owns two 64-row tiles.
//   segA(L): mainA(L) || epiB(L-1);  segB(L): mainB(L) || epiA(L).
//   Every barrier segment has 64 MFMAs/wave overlapping the other tile's
//   epilogue -> no MFMA-free convoy windows (R10 showed removing one such
//   window = +37% per-wave duty; R12 showed cross-block stagger breaks L2).
// Budget rules learned R3/R4/R11: acc total = 64 (32/tile), weights stream
// from L2 (pfA/pfB depth-2, each frag read 2x/block = R8 per-sample traffic),
// wave = 4 cf-slots x 32 samples (A-read:MFMA = 1:4, R8 ratio, not R5's).
// LDS = 2x(hbuf+xbuf padded) = 86016B -> 1 block/CU, 2 waves/SIMD, lb(512,2).
// ---------------------------------------------------------------------------

typedef _Float16 h8 __attribute__((ext_vector_type(8)));
typedef float f4 __attribute__((ext_vector_type(4)));

// fragment-linear weight offsets, in halves (byte-identical file to R8):
#define OFF_L0   0
#define OFF_L1   16384
#define OFF_L2   81920
#define OFF_L3   147456
#define OFF_L4   212992
#define OFF_L5   278528
#define OFF_L6   360448
#define OFF_L7   425984
#define OFF_OUT  491520
#define TOT_HALVES 495616
#define TOT_GROUPS (TOT_HALVES / 8)   // 61952

__global__ void nerf_prep(const float* __restrict__ W0, const float* __restrict__ W1,
                          const float* __restrict__ W2, const float* __restrict__ W3,
                          const float* __restrict__ W4, const float* __restrict__ W5,
                          const float* __restrict__ W6, const float* __restrict__ W7,
                          const float* __restrict__ Wout, _Float16* __restrict__ wf)
{
    int g = blockIdx.x * 256 + threadIdx.x;     // one 8-half fragment group
    if (g >= TOT_GROUPS) return;

    const int bounds[10] = {0, 2048, 10240, 18432, 26624, 34816, 45056, 53248, 61440, 61952};
    const float* Ws[9] = {W0, W1, W2, W3, W4, W5, W6, W7, Wout};

    int L = 0;
    while (L < 8 && g >= bounds[L + 1]) ++L;

    int t    = g - bounds[L];
    int lane = t & 63;
    int q    = t >> 6;
    int NF   = (L == 8) ? 1 : 16;
    int nf   = q % NF;
    int ks   = q / NF;
    int n    = nf * 16 + (lane & 15);
    int k0   = ks * 32 + (lane >> 4) * 8;

    const float* W = Ws[L];
    h8 v;
#pragma unroll
    for (int i = 0; i < 8; ++i) {
        int k = k0 + i;
        float val = 0.f;
        if (L == 0) {
            if (k < 63) val = W[k * 256 + n];                 // 63x256, pad k=63
        } else if (L == 5) {
            // k' < 256 -> h part (orig row 63+k'); k' >= 256 -> x part (orig row k'-256)
            if (k < 256)             val = W[(63 + k) * 256 + n];
            else if ((k - 256) < 63) val = W[(k - 256) * 256 + n];
        } else if (L == 8) {
            if (n < 4) val = W[k * 4 + n];                    // 256x4, pad n to 16
        } else {
            val = W[k * 256 + n];                             // 256x256
        }
        v[i] = (_Float16)val;
    }
    *(h8*)(wf + (size_t)g * 8) = v;
}

// slot in [0,16): which 16-col fragment of the 256-col layer output
__device__ __forceinline__ const h8* bfrag_ptr(const _Float16* __restrict__ w,
                                               int ks, int slot, int lane)
{
    return (const h8*)(w + (size_t)((ks * 16 + slot) * 64 + lane) * 8);
}

// Barrier without vmcnt drain (keeps W-prefetch loads in flight).
__device__ __forceinline__ void barrier_nodrain()
{
    asm volatile("s_waitcnt lgkmcnt(0)" ::: "memory");
    __builtin_amdgcn_s_barrier();
    __builtin_amdgcn_sched_barrier(0);
}

// One pipeline segment: main-tile layer L (read hM/xM, fill accM via pf),
// overlapped with epi-tile drain (accE -> hE), then one barrier.
// Wave: cf slots cg*4+{0..3} (ncols cg*64..cg*64+63), samples sh*32+sf*16+ln.
// pf: depth-2 rolling stream (all layer gbases even -> pslot = ks&1).
// MODE: 0 = h from hM, 1 = from xM (L0), 2 = hM then xM (L5 skip tail)
template <int KSTEPS, int MODE, bool DO_EPI, bool LAST>
__device__ __forceinline__ void seg(
    const _Float16 (&hM)[64][264], const _Float16 (&xM)[64][72],
    _Float16 (&hE)[64][264],
    const _Float16* __restrict__ wfrag, const _Float16* __restrict__ wnext,
    h8 (&pf)[2][4],
    f4 (&accM)[4][2], f4 (&accE)[4][2],
    const f4 (&bv)[4],
    int cg, int sh, int lane)
{
    const int lg = lane >> 4, ln = lane & 15;

    // init accM with bias (layer of M)
#pragma unroll
    for (int cf = 0; cf < 4; ++cf)
#pragma unroll
        for (int sf = 0; sf < 2; ++sf)
            accM[cf][sf] = bv[cf];

#pragma unroll
    for (int ks = 0; ks < KSTEPS; ++ks) {
        const int pslot = ks & 1;             // gbases all even
#pragma unroll
        for (int sf = 0; sf < 2; ++sf) {
            const int row = sh * 32 + sf * 16 + ln;
            const _Float16* ap;
            if constexpr (MODE == 1) {
                ap = &xM[row][ks * 32 + lg * 8];
            } else if constexpr (MODE == 2) {
                ap = (ks < 8) ? &hM[row][ks * 32 + lg * 8]
                              : &xM[row][(ks - 8) * 32 + lg * 8];
            } else {
                ap = &hM[row][ks * 32 + lg * 8];
            }
            h8 hfr = *(const h8*)ap;
            __builtin_amdgcn_s_setprio(1);
#pragma unroll
            for (int cf = 0; cf < 4; ++cf)
                accM[cf][sf] = __builtin_amdgcn_mfma_f32_16x16x32_f16(pf[pslot][cf], hfr, accM[cf][sf], 0, 0, 0);
            __builtin_amdgcn_s_setprio(0);
        }
        // refill consumed slot with stream position ks+2
        if (ks + 2 < KSTEPS) {
#pragma unroll
            for (int cf = 0; cf < 4; ++cf)
                pf[pslot][cf] = *bfrag_ptr(wfrag, ks + 2, cg * 4 + cf, lane);
        } else {
            if constexpr (!LAST) {
#pragma unroll
                for (int cf = 0; cf < 4; ++cf)
                    pf[pslot][cf] = *bfrag_ptr(wnext, ks + 2 - KSTEPS, cg * 4 + cf, lane);
            }
        }
        // one epi chunk of the other tile per ks (8 chunks total)
        if constexpr (DO_EPI) {
            if (ks < 8) {
                const int cfE = ks >> 1, sfE = ks & 1;
                union { _Float16 h[4]; unsigned long long u; } p;
#pragma unroll
                for (int i = 0; i < 4; ++i)
                    p.h[i] = (_Float16)fmaxf(accE[cfE][sfE][i], 0.f);
                // D layout (m89): col=ln=sample-in-16, row=lg*4+reg=ncol-in-16
                *(unsigned long long*)&hE[sh * 32 + sfE * 16 + ln][cg * 64 + cfE * 16 + lg * 4] = p.u;
            }
        }
    }
    if constexpr (DO_EPI && KSTEPS < 8) {     // short segs (L0): remaining chunks
#pragma unroll
        for (int j = KSTEPS; j < 8; ++j) {
            const int cfE = j >> 1, sfE = j & 1;
            union { _Float16 h[4]; unsigned long long u; } p;
#pragma unroll
            for (int i = 0; i < 4; ++i)
                p.h[i] = (_Float16)fmaxf(accE[cfE][sfE][i], 0.f);
            *(unsigned long long*)&hE[sh * 32 + sfE * 16 + ln][cg * 64 + cfE * 16 + lg * 4] = p.u;
        }
    }
    barrier_nodrain();
}

__global__ __launch_bounds__(512, 2) void nerf_fused(
    const float* __restrict__ x,
    const float* __restrict__ b0, const float* __restrict__ b1, const float* __restrict__ b2,
    const float* __restrict__ b3, const float* __restrict__ b4, const float* __restrict__ b5,
    const float* __restrict__ b6, const float* __restrict__ b7, const float* __restrict__ bout,
    const _Float16* __restrict__ wf,
    float* __restrict__ out)
{
    __shared__ _Float16 hA[64][264], hB[64][264];   // per-tile activations (padded)
    __shared__ _Float16 xA[64][72],  xB[64][72];    // per-tile x

    const int tid  = threadIdx.x;
    const int wid  = tid >> 6;           // 0..7
    const int lane = tid & 63;
    const int lg   = lane >> 4, ln = lane & 15;
    const int cg   = wid >> 1;           // cf group: ncols cg*64..cg*64+63
    const int sh   = wid & 1;            // sample half: rows sh*32..sh*32+31
    const int row0 = blockIdx.x * 128;

    // prologue: both streams load L0 positions 0,1
    h8 pfA[2][4], pfB[2][4];
#pragma unroll
    for (int s = 0; s < 2; ++s)
#pragma unroll
        for (int cf = 0; cf < 4; ++cf) {
            pfA[s][cf] = *bfrag_ptr(wf + OFF_L0, s, cg * 4 + cf, lane);
            pfB[s][cf] = *bfrag_ptr(wf + OFF_L0, s, cg * 4 + cf, lane);
        }

    // stage x for both tiles: rows 0..63 -> xA, 64..127 -> xB
    for (int idx = tid; idx < 128 * 64; idx += 512) {
        int r = idx >> 6, c = idx & 63;
        float v = (c < 63) ? x[(size_t)(row0 + r) * 90 + c] : 0.f;
        if (r < 64) xA[r][c] = (_Float16)v;
        else        xB[r - 64][c] = (_Float16)v;
    }
    barrier_nodrain();

    f4 accA[4][2], accB[4][2];
    f4 bv[4];
#pragma unroll
    for (int cf = 0; cf < 4; ++cf) bv[cf] = *(const f4*)&b0[cg * 64 + cf * 16 + lg * 4];

    // L0 (K=64, from xbuf)
    seg<2, 1, false, false>(hA, xA, hB, wf + OFF_L0, wf + OFF_L1, pfA, accA, accB, bv, cg, sh, lane);
    seg<2, 1, true,  false>(hB, xB, hA, wf + OFF_L0, wf + OFF_L1, pfB, accB, accA, bv, cg, sh, lane);

#pragma unroll
    for (int cf = 0; cf < 4; ++cf) bv[cf] = *(const f4*)&b1[cg * 64 + cf * 16 + lg * 4];
    seg<8, 0, true, false>(hA, xA, hB, wf + OFF_L1, wf + OFF_L2, pfA, accA, accB, bv, cg, sh, lane);
    seg<8, 0, true, false>(hB, xB, hA, wf + OFF_L1, wf + OFF_L2, pfB, accB, accA, bv, cg, sh, lane);

#pragma unroll
    for (int cf = 0; cf < 4; ++cf) bv[cf] = *(const f4*)&b2[cg * 64 + cf * 16 + lg * 4];
    seg<8, 0, true, false>(hA, xA, hB, wf + OFF_L2, wf + OFF_L3, pfA, accA, accB, bv, cg, sh, lane);
    seg<8, 0, true, false>(hB, xB, hA, wf + OFF_L2, wf + OFF_L3, pfB, accB, accA, bv, cg, sh, lane);

#pragma unroll
    for (int cf = 0; cf < 4; ++cf) bv[cf] = *(const f4*)&b3[cg * 64 + cf * 16 + lg * 4];
    seg<8, 0, true, false>(hA, xA, hB, wf + OFF_L3, wf + OFF_L4, pfA, accA, accB, bv, cg, sh, lane);
    seg<8, 0, true, false>(hB, xB, hA, wf + OFF_L3, wf + OFF_L4, pfB, accB, accA, bv, cg, sh, lane);

#pragma unroll
    for (int cf = 0; cf < 4; ++cf) bv[cf] = *(const f4*)&b4[cg * 64 + cf * 16 + lg * 4];
    seg<8, 0, true, false>(hA, xA, hB, wf + OFF_L4, wf + OFF_L5, pfA, accA, accB, bv, cg, sh, lane);
    seg<8, 0, true, false>(hB, xB, hA, wf + OFF_L4, wf + OFF_L5, pfB, accB, accA, bv, cg, sh, lane);

    // L5: 8 ks from h + 2 ks from x (skip concat), KSTEPS=10
#pragma unroll
    for (int cf = 0; cf < 4; ++cf) bv[cf] = *(const f4*)&b5[cg * 64 + cf * 16 + lg * 4];
    seg<10, 2, true, false>(hA, xA, hB, wf + OFF_L5, wf + OFF_L6, pfA, accA, accB, bv, cg, sh, lane);
    seg<10, 2, true, false>(hB, xB, hA, wf + OFF_L5, wf + OFF_L6, pfB, accB, accA, bv, cg, sh, lane);

#pragma unroll
    for (int cf = 0; cf < 4; ++cf) bv[cf] = *(const f4*)&b6[cg * 64 + cf * 16 + lg * 4];
    seg<8, 0, true, false>(hA, xA, hB, wf + OFF_L6, wf + OFF_L7, pfA, accA, accB, bv, cg, sh, lane);
    seg<8, 0, true, false>(hB, xB, hA, wf + OFF_L6, wf + OFF_L7, pfB, accB, accA, bv, cg, sh, lane);

#pragma unroll
    for (int cf = 0; cf < 4; ++cf) bv[cf] = *(const f4*)&b7[cg * 64 + cf * 16 + lg * 4];
    seg<8, 0, true, true>(hA, xA, hB, wf + OFF_L7, wf + OFF_L7, pfA, accA, accB, bv, cg, sh, lane);
    seg<8, 0, true, true>(hB, xB, hA, wf + OFF_L7, wf + OFF_L7, pfB, accB, accA, bv, cg, sh, lane);

    // ---- final: epiB(L7) (all waves) || outA (waves 0-3); barrier; outB (waves 4-7)
#pragma unroll
    for (int j = 0; j < 8; ++j) {
        const int cfE = j >> 1, sfE = j & 1;
        union { _Float16 h[4]; unsigned long long u; } p;
#pragma unroll
        for (int i = 0; i < 4; ++i)
            p.h[i] = (_Float16)fmaxf(accB[cfE][sfE][i], 0.f);
        *(unsigned long long*)&hB[sh * 32 + sfE * 16 + ln][cg * 64 + cfE * 16 + lg * 4] = p.u;
    }
    if (wid < 4) {          // outA: hA is complete (epiA(L7) done in last segB)
        f4 oacc;
#pragma unroll
        for (int i = 0; i < 4; ++i) oacc[i] = 0.f;
#pragma unroll
        for (int ks = 0; ks < 8; ++ks) {
            h8 bfr = *(const h8*)(wf + OFF_OUT + (size_t)(ks * 64 + lane) * 8);
            h8 afr = *(const h8*)&hA[wid * 16 + ln][ks * 32 + lg * 8];
            oacc = __builtin_amdgcn_mfma_f32_16x16x32_f16(afr, bfr, oacc, 0, 0, 0);
        }
        if (ln < 4) {
            float bo = bout[ln];
#pragma unroll
            for (int i = 0; i < 4; ++i) {
                int r = row0 + wid * 16 + lg * 4 + i;
                out[(size_t)r * 4 + ln] = oacc[i] + bo;
            }
        }
    }
    barrier_nodrain();
    if (wid >= 4) {         // outB: hB complete after barrier
        const int w2 = wid - 4;
        f4 oacc;
#pragma unroll
        for (int i = 0; i < 4; ++i) oacc[i] = 0.f;
#pragma unroll
        for (int ks = 0; ks < 8; ++ks) {
            h8 bfr = *(const h8*)(wf + OFF_OUT + (size_t)(ks * 64 + lane) * 8);
            h8 afr = *(const h8*)&hB[w2 * 16 + ln][ks * 32 + lg * 8];
            oacc = __builtin_amdgcn_mfma_f32_16x16x32_f16(afr, bfr, oacc, 0, 0, 0);
        }
        if (ln < 4) {
            float bo = bout[ln];
#pragma unroll
            for (int i = 0; i < 4; ++i) {
                int r = row0 + 64 + w2 * 16 + lg * 4 + i;
                out[(size_t)r * 4 + ln] = oacc[i] + bo;
            }
        }
    }
}

extern "C" void kernel_launch(void* const* d_in, const int* in_sizes, int n_in,
                              void* d_out, int out_size, void* d_ws, size_t ws_size,
                              hipStream_t stream)
{
    const float* x = (const float*)d_in[0];
    const float* W[9];
    const float* b[9];
    for (int i = 0; i < 8; ++i) {
        W[i] = (const float*)d_in[1 + 2 * i];
        b[i] = (const float*)d_in[2 + 2 * i];
    }
    W[8] = (const float*)d_in[17];   // Wout
    b[8] = (const float*)d_in[18];   // bout

    _Float16* wf = (_Float16*)d_ws;

    nerf_prep<<<(TOT_GROUPS + 255) / 256, 256, 0, stream>>>(
        W[0], W[1], W[2], W[3], W[4], W[5], W[6], W[7], W[8], wf);

    nerf_fused<<<262144 / 128, 512, 0, stream>>>(
        x, b[0], b[1], b[2], b[3], b[4], b[5], b[6], b[7], b[8], wf,
        (float*)d_out);
}

// Round 14
// 253.259 us; speedup vs baseline: 1.2337x; 1.2337x over previous
//
#include <hip/hip_runtime.h>

// ---------------------------------------------------------------------------
// Fused NeRF MLP forward: 262144 rows, 63-in, 8x256 hidden + skip at L4->L5,
// 4-dim output. fp16 MFMA (16x16x32, swapped operands) with fp32 accum.
//
// R14 = R8 (best: 277us profiled / 234.9us headline) + cvt-hoist ONLY
// (R12 tested hoist+stagger together; stagger poisoned L2 (FETCH +44%).
// This isolates the hoist: relu+cvt+pack into registers BEFORE the WAR
// barrier; only the 16 ds_write_b64 remain in the barrier-locked window).
//
// Structure facts established R2-R13: wall/layer ~17k cyc invariant to
// occupancy (12-16 waves), MFMA shape, prefetch depth, barrier count at
// fixed occupancy, tile rotation/scale, intra-block anti-phase, and
// cross-block stagger => 2-barrier chained-layer structure plateau
// (m233-class). acc must stay <=64 regs (R4/R11 spill rule); gn=4/gm=1
// tile is the traffic optimum (R5/R6).
// ---------------------------------------------------------------------------

typedef _Float16 h8 __attribute__((ext_vector_type(8)));
typedef float f4 __attribute__((ext_vector_type(4)));

// fragment-linear weight offsets, in halves:
#define OFF_L0   0
#define OFF_L1   16384
#define OFF_L2   81920
#define OFF_L3   147456
#define OFF_L4   212992
#define OFF_L5   278528
#define OFF_L6   360448
#define OFF_L7   425984
#define OFF_OUT  491520
#define TOT_HALVES 495616
#define TOT_GROUPS (TOT_HALVES / 8)   // 61952

__global__ void nerf_prep(const float* __restrict__ W0, const float* __restrict__ W1,
                          const float* __restrict__ W2, const float* __restrict__ W3,
                          const float* __restrict__ W4, const float* __restrict__ W5,
                          const float* __restrict__ W6, const float* __restrict__ W7,
                          const float* __restrict__ Wout, _Float16* __restrict__ wf)
{
    int g = blockIdx.x * 256 + threadIdx.x;     // one 8-half fragment group
    if (g >= TOT_GROUPS) return;

    const int bounds[10] = {0, 2048, 10240, 18432, 26624, 34816, 45056, 53248, 61440, 61952};
    const float* Ws[9] = {W0, W1, W2, W3, W4, W5, W6, W7, Wout};

    int L = 0;
    while (L < 8 && g >= bounds[L + 1]) ++L;

    int t    = g - bounds[L];
    int lane = t & 63;
    int q    = t >> 6;
    int NF   = (L == 8) ? 1 : 16;
    int nf   = q % NF;
    int ks   = q / NF;
    int n    = nf * 16 + (lane & 15);
    int k0   = ks * 32 + (lane >> 4) * 8;

    const float* W = Ws[L];
    h8 v;
#pragma unroll
    for (int i = 0; i < 8; ++i) {
        int k = k0 + i;
        float val = 0.f;
        if (L == 0) {
            if (k < 63) val = W[k * 256 + n];                 // 63x256, pad k=63
        } else if (L == 5) {
            // k' < 256 -> h part (orig row 63+k'); k' >= 256 -> x part (orig row k'-256)
            if (k < 256)             val = W[(63 + k) * 256 + n];
            else if ((k - 256) < 63) val = W[(k - 256) * 256 + n];
        } else if (L == 8) {
            if (n < 4) val = W[k * 4 + n];                    // 256x4, pad n to 16
        } else {
            val = W[k * 256 + n];                             // 256x256
        }
        v[i] = (_Float16)val;
    }
    *(h8*)(wf + (size_t)g * 8) = v;
}

__device__ __forceinline__ const h8* bfrag_ptr(const _Float16* __restrict__ w,
                                               int ks, int wid, int nf, int lane)
{
    return (const h8*)(w + (size_t)((ks * 16 + (wid * 4 + nf)) * 64 + lane) * 8);
}

// Barrier without vmcnt drain (keeps cross-layer W-prefetch loads in flight).
__device__ __forceinline__ void barrier_nodrain()
{
    asm volatile("s_waitcnt lgkmcnt(0)" ::: "memory");
    __builtin_amdgcn_s_barrier();
    __builtin_amdgcn_sched_barrier(0);
}

// MODE: 0 = h from hbuf, 1 = h from xbuf (layer 0), 2 = hbuf then xbuf (layer 5)
// pf: depth-3 rolling W prefetch (slot = global kstep % 3, GB3 = gbase % 3).
template <int KSTEPS, int MODE, int GB3, bool LAST>
__device__ __forceinline__ void mlp_layer(_Float16 (&hbuf)[64][264], _Float16 (&xbuf)[64][72],
                                          const _Float16* __restrict__ wfrag,
                                          const _Float16* __restrict__ wnext,
                                          const float* __restrict__ bias,
                                          int wid, int lane, h8 (&pf)[3][4])
{
    const int lg = lane >> 4, ln = lane & 15;

    // bias as float4 per cf: ncols wid*64 + cf*16 + lg*4 + (0..3)
    f4 bv[4];
#pragma unroll
    for (int cf = 0; cf < 4; ++cf)
        bv[cf] = *(const f4*)&bias[wid * 64 + cf * 16 + lg * 4];

    // accumulator INITIALIZED with bias
    f4 acc[4][4];   // [cf][sf]
#pragma unroll
    for (int cf = 0; cf < 4; ++cf)
#pragma unroll
        for (int sf = 0; sf < 4; ++sf)
            acc[cf][sf] = bv[cf];

#pragma unroll
    for (int ks = 0; ks < KSTEPS; ++ks) {
        const int slot = (GB3 + ks) % 3;      // folds to constant after unroll
        __builtin_amdgcn_s_setprio(1);
        h8 hfr[4];
#pragma unroll
        for (int sf = 0; sf < 4; ++sf) {
            const _Float16* ap;
            if constexpr (MODE == 1) {
                ap = &xbuf[sf * 16 + ln][ks * 32 + lg * 8];
            } else if constexpr (MODE == 2) {
                ap = (ks < 8) ? &hbuf[sf * 16 + ln][ks * 32 + lg * 8]
                              : &xbuf[sf * 16 + ln][(ks - 8) * 32 + lg * 8];
            } else {
                ap = &hbuf[sf * 16 + ln][ks * 32 + lg * 8];
            }
            hfr[sf] = *(const h8*)ap;
        }
#pragma unroll
        for (int cf = 0; cf < 4; ++cf)
#pragma unroll
            for (int sf = 0; sf < 4; ++sf)
                acc[cf][sf] = __builtin_amdgcn_mfma_f32_16x16x32_f16(pf[slot][cf], hfr[sf], acc[cf][sf], 0, 0, 0);
        __builtin_amdgcn_s_setprio(0);
        // refill the slot just consumed with global kstep g+3
        if (ks + 3 < KSTEPS) {
#pragma unroll
            for (int cf = 0; cf < 4; ++cf)
                pf[slot][cf] = *bfrag_ptr(wfrag, ks + 3, wid, cf, lane);
        } else {
            if constexpr (!LAST) {
#pragma unroll
                for (int cf = 0; cf < 4; ++cf)
                    pf[slot][cf] = *bfrag_ptr(wnext, ks + 3 - KSTEPS, wid, cf, lane);
            }
        }
    }

    // cvt-HOIST: relu + cvt + pack BEFORE the barrier (overlaps other blocks'
    // MFMA phases); only the 16 ds_write_b64 sit in the barrier-locked window.
    unsigned long long pu[4][4];
#pragma unroll
    for (int cf = 0; cf < 4; ++cf) {
#pragma unroll
        for (int sf = 0; sf < 4; ++sf) {
            union { _Float16 h[4]; unsigned long long u; } p;
#pragma unroll
            for (int i = 0; i < 4; ++i)
                p.h[i] = (_Float16)fmaxf(acc[cf][sf][i], 0.f);
            pu[cf][sf] = p.u;
        }
    }

    barrier_nodrain();   // WAR: everyone done reading hbuf

    // D layout (m89): col=ln=sample-within-16, row=lg*4+reg=ncol-within-16
#pragma unroll
    for (int cf = 0; cf < 4; ++cf)
#pragma unroll
        for (int sf = 0; sf < 4; ++sf)
            *(unsigned long long*)&hbuf[sf * 16 + ln][wid * 64 + cf * 16 + lg * 4] = pu[cf][sf];

    barrier_nodrain();   // RAW: writes visible before next layer's reads
}

__global__ __launch_bounds__(256, 3) void nerf_fused(
    const float* __restrict__ x,
    const float* __restrict__ b0, const float* __restrict__ b1, const float* __restrict__ b2,
    const float* __restrict__ b3, const float* __restrict__ b4, const float* __restrict__ b5,
    const float* __restrict__ b6, const float* __restrict__ b7, const float* __restrict__ bout,
    const _Float16* __restrict__ wf,
    float* __restrict__ out)
{
    __shared__ _Float16 hbuf[64][264];   // proven padded layout
    __shared__ _Float16 xbuf[64][72];

    const int tid  = threadIdx.x;
    const int wid  = tid >> 6;
    const int lane = tid & 63;
    const int lg   = lane >> 4, ln = lane & 15;
    const int row0 = blockIdx.x * 64;

    // prologue: globals 0,1,2 = L0 ks0, L0 ks1, L1 ks0 into slots 0,1,2
    h8 pf[3][4];
#pragma unroll
    for (int cf = 0; cf < 4; ++cf) {
        pf[0][cf] = *bfrag_ptr(wf + OFF_L0, 0, wid, cf, lane);
        pf[1][cf] = *bfrag_ptr(wf + OFF_L0, 1, wid, cf, lane);
        pf[2][cf] = *bfrag_ptr(wf + OFF_L1, 0, wid, cf, lane);
    }

    // stage x[:, 0:63] -> fp16, zero-pad col 63
    for (int idx = tid; idx < 64 * 64; idx += 256) {
        int r = idx >> 6, c = idx & 63;
        float v = (c < 63) ? x[(size_t)(row0 + r) * 90 + c] : 0.f;
        xbuf[r][c] = (_Float16)v;
    }
    barrier_nodrain();

    // gbase per layer: 0,2,10,18,26,34,44,52 -> %3 = 0,2,1,0,2,1,2,1
    mlp_layer<2,  1, 0, false>(hbuf, xbuf, wf + OFF_L0, wf + OFF_L1, b0, wid, lane, pf);
    mlp_layer<8,  0, 2, false>(hbuf, xbuf, wf + OFF_L1, wf + OFF_L2, b1, wid, lane, pf);
    mlp_layer<8,  0, 1, false>(hbuf, xbuf, wf + OFF_L2, wf + OFF_L3, b2, wid, lane, pf);
    mlp_layer<8,  0, 0, false>(hbuf, xbuf, wf + OFF_L3, wf + OFF_L4, b3, wid, lane, pf);
    mlp_layer<8,  0, 2, false>(hbuf, xbuf, wf + OFF_L4, wf + OFF_L5, b4, wid, lane, pf);
    mlp_layer<10, 2, 1, false>(hbuf, xbuf, wf + OFF_L5, wf + OFF_L6, b5, wid, lane, pf);
    mlp_layer<8,  0, 2, false>(hbuf, xbuf, wf + OFF_L6, wf + OFF_L7, b6, wid, lane, pf);
    mlp_layer<8,  0, 1, true >(hbuf, xbuf, wf + OFF_L7, wf + OFF_L7, b7, wid, lane, pf);

    // output layer 256 -> 4 (padded to 16 cols), UNswapped path:
    // wave wid owns rows [16*wid, 16*wid+16)
    f4 oacc;
#pragma unroll
    for (int i = 0; i < 4; ++i) oacc[i] = 0.f;
#pragma unroll
    for (int ks = 0; ks < 8; ++ks) {
        h8 bfr = *(const h8*)(wf + OFF_OUT + (size_t)(ks * 64 + lane) * 8);
        h8 afr = *(const h8*)&hbuf[wid * 16 + ln][ks * 32 + lg * 8];
        oacc = __builtin_amdgcn_mfma_f32_16x16x32_f16(afr, bfr, oacc, 0, 0, 0);
    }
    if (ln < 4) {
        float bo = bout[ln];
#pragma unroll
        for (int i = 0; i < 4; ++i) {
            int r = row0 + wid * 16 + lg * 4 + i;
            out[(size_t)r * 4 + ln] = oacc[i] + bo;
        }
    }
}

extern "C" void kernel_launch(void* const* d_in, const int* in_sizes, int n_in,
                              void* d_out, int out_size, void* d_ws, size_t ws_size,
                              hipStream_t stream)
{
    const float* x = (const float*)d_in[0];
    const float* W[9];
    const float* b[9];
    for (int i = 0; i < 8; ++i) {
        W[i] = (const float*)d_in[1 + 2 * i];
        b[i] = (const float*)d_in[2 + 2 * i];
    }
    W[8] = (const float*)d_in[17];   // Wout
    b[8] = (const float*)d_in[18];   // bout

    _Float16* wf = (_Float16*)d_ws;

    nerf_prep<<<(TOT_GROUPS + 255) / 256, 256, 0, stream>>>(
        W[0], W[1], W[2], W[3], W[4], W[5], W[6], W[7], W[8], wf);

    nerf_fused<<<262144 / 64, 256, 0, stream>>>(
        x, b[0], b[1], b[2], b[3], b[4], b[5], b[6], b[7], b[8], wf,
        (float*)d_out);
}

// Round 15
// 235.211 us; speedup vs baseline: 1.3283x; 1.0767x over previous
//
#include <hip/hip_runtime.h>

// ---------------------------------------------------------------------------
// Fused NeRF MLP forward: 262144 rows, 63-in, 8x256 hidden + skip at L4->L5,
// 4-dim output. fp16 MFMA (16x16x32, swapped operands) with fp32 accum.
//
// FINAL = R8 exactly (best measured: 277us profiled / 234.9us headline,
// MfmaUtil 44% = ~930 TF = 45% of 16x16x32 ubench ceiling).
//
// Established facts (R2-R14):
//  - Wall ~17k cyc/layer is invariant to: occupancy 12<->16 waves (R5),
//    tile rotation (R6), W-prefetch depth 2/3 + nodrain barriers + setprio
//    (R7), 32x32x16 shape (R9), single-barrier dbuf (R10), M=128 (R11),
//    cross-block stagger (R12: breaks L2, FETCH +44%), intra-block dual-tile
//    anti-phase (R13), cvt-hoist (R14: spills).
//  - Register rule: acc <= 64 regs; any +32 live regs across the layer
//    barrier spills to scratch (R4, R11, R14).
//  - gn=4/gm=1 wave tile is the traffic optimum (R5: LDS-amp, R6: L2-amp).
//  - This is the m233-class 2-barrier plateau; deep counted-vmcnt pipelines
//    don't apply (true inter-layer data dependency).
// ---------------------------------------------------------------------------

typedef _Float16 h8 __attribute__((ext_vector_type(8)));
typedef float f4 __attribute__((ext_vector_type(4)));

// fragment-linear weight offsets, in halves:
// L0 K=64, L1..L4 K=256, L5 K=320, L6,L7 K=256, OUT K=256 (NF=1, n padded to 16)
#define OFF_L0   0
#define OFF_L1   16384
#define OFF_L2   81920
#define OFF_L3   147456
#define OFF_L4   212992
#define OFF_L5   278528
#define OFF_L6   360448
#define OFF_L7   425984
#define OFF_OUT  491520
#define TOT_HALVES 495616
#define TOT_GROUPS (TOT_HALVES / 8)   // 61952

__global__ void nerf_prep(const float* __restrict__ W0, const float* __restrict__ W1,
                          const float* __restrict__ W2, const float* __restrict__ W3,
                          const float* __restrict__ W4, const float* __restrict__ W5,
                          const float* __restrict__ W6, const float* __restrict__ W7,
                          const float* __restrict__ Wout, _Float16* __restrict__ wf)
{
    int g = blockIdx.x * 256 + threadIdx.x;     // one 8-half fragment group
    if (g >= TOT_GROUPS) return;

    const int bounds[10] = {0, 2048, 10240, 18432, 26624, 34816, 45056, 53248, 61440, 61952};
    const float* Ws[9] = {W0, W1, W2, W3, W4, W5, W6, W7, Wout};

    int L = 0;
    while (L < 8 && g >= bounds[L + 1]) ++L;

    int t    = g - bounds[L];
    int lane = t & 63;
    int q    = t >> 6;
    int NF   = (L == 8) ? 1 : 16;
    int nf   = q % NF;
    int ks   = q / NF;
    int n    = nf * 16 + (lane & 15);
    int k0   = ks * 32 + (lane >> 4) * 8;

    const float* W = Ws[L];
    h8 v;
#pragma unroll
    for (int i = 0; i < 8; ++i) {
        int k = k0 + i;
        float val = 0.f;
        if (L == 0) {
            if (k < 63) val = W[k * 256 + n];                 // 63x256, pad k=63
        } else if (L == 5) {
            // k' < 256 -> h part (orig row 63+k'); k' >= 256 -> x part (orig row k'-256)
            if (k < 256)             val = W[(63 + k) * 256 + n];
            else if ((k - 256) < 63) val = W[(k - 256) * 256 + n];
        } else if (L == 8) {
            if (n < 4) val = W[k * 4 + n];                    // 256x4, pad n to 16
        } else {
            val = W[k * 256 + n];                             // 256x256
        }
        v[i] = (_Float16)val;
    }
    *(h8*)(wf + (size_t)g * 8) = v;
}

__device__ __forceinline__ const h8* bfrag_ptr(const _Float16* __restrict__ w,
                                               int ks, int wid, int nf, int lane)
{
    return (const h8*)(w + (size_t)((ks * 16 + (wid * 4 + nf)) * 64 + lane) * 8);
}

// Barrier that does NOT drain vmcnt: keeps cross-layer W-prefetch loads in
// flight. lgkmcnt(0) orders all LDS reads/writes (WAR and RAW both safe);
// sched_barrier(0) stops the compiler from moving LDS ops across it.
__device__ __forceinline__ void barrier_nodrain()
{
    asm volatile("s_waitcnt lgkmcnt(0)" ::: "memory");
    __builtin_amdgcn_s_barrier();
    __builtin_amdgcn_sched_barrier(0);
}

// MODE: 0 = h from hbuf, 1 = h from xbuf (layer 0), 2 = hbuf then xbuf (layer 5)
// pf: depth-3 rolling prefetch of W-fragments (consumed as MFMA A operand).
// acc[cf][sf]: D[ncol][sample] per fragment pair; initialized with bias.
template <int KSTEPS, int MODE, int GB3, bool LAST>
__device__ __forceinline__ void mlp_layer(_Float16 (&hbuf)[64][264], _Float16 (&xbuf)[64][72],
                                          const _Float16* __restrict__ wfrag,
                                          const _Float16* __restrict__ wnext,
                                          const float* __restrict__ bias,
                                          int wid, int lane, h8 (&pf)[3][4])
{
    const int lg = lane >> 4, ln = lane & 15;

    // bias as float4 per cf: ncols wid*64 + cf*16 + lg*4 + (0..3)  (16B aligned)
    f4 bv[4];
#pragma unroll
    for (int cf = 0; cf < 4; ++cf)
        bv[cf] = *(const f4*)&bias[wid * 64 + cf * 16 + lg * 4];

    // accumulator INITIALIZED with bias (saves zero-init + epilogue add)
    f4 acc[4][4];   // [cf][sf]
#pragma unroll
    for (int cf = 0; cf < 4; ++cf)
#pragma unroll
        for (int sf = 0; sf < 4; ++sf)
            acc[cf][sf] = bv[cf];

#pragma unroll
    for (int ks = 0; ks < KSTEPS; ++ks) {
        const int slot = (GB3 + ks) % 3;      // folds to constant after unroll
        __builtin_amdgcn_s_setprio(1);
        h8 hfr[4];
#pragma unroll
        for (int sf = 0; sf < 4; ++sf) {
            const _Float16* ap;
            if constexpr (MODE == 1) {
                ap = &xbuf[sf * 16 + ln][ks * 32 + lg * 8];
            } else if constexpr (MODE == 2) {
                ap = (ks < 8) ? &hbuf[sf * 16 + ln][ks * 32 + lg * 8]
                              : &xbuf[sf * 16 + ln][(ks - 8) * 32 + lg * 8];
            } else {
                ap = &hbuf[sf * 16 + ln][ks * 32 + lg * 8];
            }
            hfr[sf] = *(const h8*)ap;
        }
#pragma unroll
        for (int cf = 0; cf < 4; ++cf)
#pragma unroll
            for (int sf = 0; sf < 4; ++sf)
                acc[cf][sf] = __builtin_amdgcn_mfma_f32_16x16x32_f16(pf[slot][cf], hfr[sf], acc[cf][sf], 0, 0, 0);
        __builtin_amdgcn_s_setprio(0);
        // refill the slot just consumed with global kstep g+3
        if (ks + 3 < KSTEPS) {
#pragma unroll
            for (int cf = 0; cf < 4; ++cf)
                pf[slot][cf] = *bfrag_ptr(wfrag, ks + 3, wid, cf, lane);
        } else {
            if constexpr (!LAST) {
#pragma unroll
                for (int cf = 0; cf < 4; ++cf)
                    pf[slot][cf] = *bfrag_ptr(wnext, ks + 3 - KSTEPS, wid, cf, lane);
            }
        }
    }

    barrier_nodrain();   // WAR: everyone done reading hbuf

    // packed epilogue: relu + cvt, 4 ncols -> one ds_write_b64 per (cf,sf)
    // D layout (m89): col=ln=sample-within-16, row=lg*4+reg=ncol-within-16
#pragma unroll
    for (int cf = 0; cf < 4; ++cf) {
#pragma unroll
        for (int sf = 0; sf < 4; ++sf) {
            union { _Float16 h[4]; unsigned long long u; } p;
#pragma unroll
            for (int i = 0; i < 4; ++i)
                p.h[i] = (_Float16)fmaxf(acc[cf][sf][i], 0.f);
            *(unsigned long long*)&hbuf[sf * 16 + ln][wid * 64 + cf * 16 + lg * 4] = p.u;
        }
    }
    barrier_nodrain();   // RAW: writes visible before next layer's reads
}

__global__ __launch_bounds__(256, 3) void nerf_fused(
    const float* __restrict__ x,
    const float* __restrict__ b0, const float* __restrict__ b1, const float* __restrict__ b2,
    const float* __restrict__ b3, const float* __restrict__ b4, const float* __restrict__ b5,
    const float* __restrict__ b6, const float* __restrict__ b7, const float* __restrict__ bout,
    const _Float16* __restrict__ wf,
    float* __restrict__ out)
{
    __shared__ _Float16 hbuf[64][264];   // 256 + 8 pad halves per row (proven layout)
    __shared__ _Float16 xbuf[64][72];    // 64 (63 real + 1 zero) + pad

    const int tid  = threadIdx.x;
    const int wid  = tid >> 6;
    const int lane = tid & 63;
    const int lg   = lane >> 4, ln = lane & 15;
    const int row0 = blockIdx.x * 64;

    // prologue: globals 0,1,2 = L0 ks0, L0 ks1, L1 ks0 into slots 0,1,2
    h8 pf[3][4];
#pragma unroll
    for (int cf = 0; cf < 4; ++cf) {
        pf[0][cf] = *bfrag_ptr(wf + OFF_L0, 0, wid, cf, lane);
        pf[1][cf] = *bfrag_ptr(wf + OFF_L0, 1, wid, cf, lane);
        pf[2][cf] = *bfrag_ptr(wf + OFF_L1, 0, wid, cf, lane);
    }

    // stage x[:, 0:63] -> fp16, zero-pad col 63
    for (int idx = tid; idx < 64 * 64; idx += 256) {
        int r = idx >> 6, c = idx & 63;
        float v = (c < 63) ? x[(size_t)(row0 + r) * 90 + c] : 0.f;
        xbuf[r][c] = (_Float16)v;
    }
    barrier_nodrain();

    // gbase per layer: 0,2,10,18,26,34,44,52 -> %3 = 0,2,1,0,2,1,2,1
    mlp_layer<2,  1, 0, false>(hbuf, xbuf, wf + OFF_L0, wf + OFF_L1, b0, wid, lane, pf);
    mlp_layer<8,  0, 2, false>(hbuf, xbuf, wf + OFF_L1, wf + OFF_L2, b1, wid, lane, pf);
    mlp_layer<8,  0, 1, false>(hbuf, xbuf, wf + OFF_L2, wf + OFF_L3, b2, wid, lane, pf);
    mlp_layer<8,  0, 0, false>(hbuf, xbuf, wf + OFF_L3, wf + OFF_L4, b3, wid, lane, pf);
    mlp_layer<8,  0, 2, false>(hbuf, xbuf, wf + OFF_L4, wf + OFF_L5, b4, wid, lane, pf);
    mlp_layer<10, 2, 1, false>(hbuf, xbuf, wf + OFF_L5, wf + OFF_L6, b5, wid, lane, pf);
    mlp_layer<8,  0, 2, false>(hbuf, xbuf, wf + OFF_L6, wf + OFF_L7, b6, wid, lane, pf);
    mlp_layer<8,  0, 1, true >(hbuf, xbuf, wf + OFF_L7, wf + OFF_L7, b7, wid, lane, pf);

    // output layer 256 -> 4 (padded to 16 cols), UNswapped (original path):
    // wave wid owns rows [16*wid, 16*wid+16)
    f4 oacc;
#pragma unroll
    for (int i = 0; i < 4; ++i) oacc[i] = 0.f;
#pragma unroll
    for (int ks = 0; ks < 8; ++ks) {
        h8 bfr = *(const h8*)(wf + OFF_OUT + (size_t)(ks * 64 + lane) * 8);
        h8 afr = *(const h8*)&hbuf[wid * 16 + ln][ks * 32 + lg * 8];
        oacc = __builtin_amdgcn_mfma_f32_16x16x32_f16(afr, bfr, oacc, 0, 0, 0);
    }
    if (ln < 4) {
        float bo = bout[ln];
#pragma unroll
        for (int i = 0; i < 4; ++i) {
            int r = row0 + wid * 16 + lg * 4 + i;
            out[(size_t)r * 4 + ln] = oacc[i] + bo;
        }
    }
}

extern "C" void kernel_launch(void* const* d_in, const int* in_sizes, int n_in,
                              void* d_out, int out_size, void* d_ws, size_t ws_size,
                              hipStream_t stream)
{
    const float* x = (const float*)d_in[0];
    const float* W[9];
    const float* b[9];
    for (int i = 0; i < 8; ++i) {
        W[i] = (const float*)d_in[1 + 2 * i];
        b[i] = (const float*)d_in[2 + 2 * i];
    }
    W[8] = (const float*)d_in[17];   // Wout
    b[8] = (const float*)d_in[18];   // bout

    _Float16* wf = (_Float16*)d_ws;

    nerf_prep<<<(TOT_GROUPS + 255) / 256, 256, 0, stream>>>(
        W[0], W[1], W[2], W[3], W[4], W[5], W[6], W[7], W[8], wf);

    nerf_fused<<<262144 / 64, 256, 0, stream>>>(
        x, b[0], b[1], b[2], b[3], b[4], b[5], b[6], b[7], b[8], wf,
        (float*)d_out);
}